// Round 1
// baseline (200.512 us; speedup 1.0000x reference)
//
#include <hip/hip_runtime.h>
#include <cstdint>
#include <cstddef>

// ---------------- types ----------------
typedef __attribute__((ext_vector_type(4))) float  floatx4;
typedef __attribute__((ext_vector_type(8))) __bf16 bf16x8;
typedef __attribute__((ext_vector_type(8))) unsigned short u16x8;

#define M_TOT 16384   // B*S
#define N_TOT 2048    // D_OUT
#define K_TOT 2048    // D_IN
#define NBATCH 8
#define RLORA 16

// f32 -> bf16 round-to-nearest-even (no NaN handling needed; inputs are finite)
__device__ __forceinline__ unsigned short f32_to_bf16(float f) {
  unsigned u = __float_as_uint(f);
  u += 0x7fffu + ((u >> 16) & 1u);
  return (unsigned short)(u >> 16);
}

// async global->LDS, 16B per lane. LDS dest must be wave-uniform (HW adds lane*16).
#define GLOAD_LDS16(gp, lp)                                                        \
  __builtin_amdgcn_global_load_lds((__attribute__((address_space(1))) void*)(void*)(gp), \
                                   (__attribute__((address_space(3))) void*)(void*)(lp), \
                                   16, 0, 0)

// ---------------- elementwise f32 -> bf16 (8 elems/thread) ----------------
__global__ void k_convert(const float* __restrict__ in, unsigned short* __restrict__ out, int n8) {
  int i = blockIdx.x * blockDim.x + threadIdx.x;
  if (i >= n8) return;
  const float4* p = (const float4*)in + (size_t)i * 2;
  float4 v0 = p[0], v1 = p[1];
  u16x8 o;
  o[0] = f32_to_bf16(v0.x); o[1] = f32_to_bf16(v0.y);
  o[2] = f32_to_bf16(v0.z); o[3] = f32_to_bf16(v0.w);
  o[4] = f32_to_bf16(v1.x); o[5] = f32_to_bf16(v1.y);
  o[6] = f32_to_bf16(v1.z); o[7] = f32_to_bf16(v1.w);
  *(u16x8*)(out + (size_t)i * 8) = o;
}

// ---------------- A_params [8][2048][16] f32 -> [8*2048][32] bf16, zero-padded ----------------
__global__ void k_convert_a(const float* __restrict__ A, unsigned short* __restrict__ abf) {
  int row = blockIdx.x * blockDim.x + threadIdx.x;  // 0..16383  (b*2048 + o)
  if (row >= NBATCH * N_TOT) return;
  const float4* p = (const float4*)(A + (size_t)row * RLORA);
  float4 v0 = p[0], v1 = p[1], v2 = p[2], v3 = p[3];
  u16x8 lo, hi2, z = {0,0,0,0,0,0,0,0};
  lo[0] = f32_to_bf16(v0.x); lo[1] = f32_to_bf16(v0.y);
  lo[2] = f32_to_bf16(v0.z); lo[3] = f32_to_bf16(v0.w);
  lo[4] = f32_to_bf16(v1.x); lo[5] = f32_to_bf16(v1.y);
  lo[6] = f32_to_bf16(v1.z); lo[7] = f32_to_bf16(v1.w);
  hi2[0] = f32_to_bf16(v2.x); hi2[1] = f32_to_bf16(v2.y);
  hi2[2] = f32_to_bf16(v2.z); hi2[3] = f32_to_bf16(v2.w);
  hi2[4] = f32_to_bf16(v3.x); hi2[5] = f32_to_bf16(v3.y);
  hi2[6] = f32_to_bf16(v3.z); hi2[7] = f32_to_bf16(v3.w);
  u16x8* dst = (u16x8*)(abf + (size_t)row * 32);
  dst[0] = lo; dst[1] = hi2; dst[2] = z; dst[3] = z;
}

// ---------------- inter[m][r] = sum_i xbf[m][i] * bpbf[b][r][i]  (MFMA, K split over 4 waves) ----------------
__global__ __launch_bounds__(256) void k_inter(const unsigned short* __restrict__ xbf,
                                               const unsigned short* __restrict__ bpbf,
                                               unsigned short* __restrict__ interbf) {
  const int tid  = threadIdx.x;
  const int lane = tid & 63;
  const int wv   = tid >> 6;
  const int l15  = lane & 15;
  const int hi   = lane >> 4;
  const int m0   = blockIdx.x * 64;          // 64 rows per block
  const int bb   = m0 >> 11;                 // batch index

  floatx4 zero = {0.f, 0.f, 0.f, 0.f};
  floatx4 acc[4] = {zero, zero, zero, zero};

  const unsigned short* bpb = bpbf + (size_t)bb * (RLORA * K_TOT);
  const int kb0 = wv * 512;                  // each wave covers 512 of K
  for (int kb = kb0; kb < kb0 + 512; kb += 32) {
    bf16x8 bfr = *(const bf16x8*)(bpb + (size_t)l15 * K_TOT + kb + hi * 8);
    #pragma unroll
    for (int mi = 0; mi < 4; ++mi) {
      bf16x8 afr = *(const bf16x8*)(xbf + (size_t)(m0 + mi * 16 + l15) * K_TOT + kb + hi * 8);
      acc[mi] = __builtin_amdgcn_mfma_f32_16x16x32_bf16(afr, bfr, acc[mi], 0, 0, 0);
    }
  }

  __shared__ floatx4 red[4][4][64];          // [wave][mi][lane] = 16 KB
  #pragma unroll
  for (int mi = 0; mi < 4; ++mi) red[wv][mi][lane] = acc[mi];
  __syncthreads();
  if (wv == 0) {
    #pragma unroll
    for (int mi = 0; mi < 4; ++mi) {
      floatx4 s = red[0][mi][lane] + red[1][mi][lane] + red[2][mi][lane] + red[3][mi][lane];
      #pragma unroll
      for (int j = 0; j < 4; ++j) {
        int m = m0 + mi * 16 + hi * 4 + j;   // C/D layout: row = (lane>>4)*4 + j, col = l15
        interbf[(size_t)m * 32 + l15] = f32_to_bf16(s[j]);
        interbf[(size_t)m * 32 + 16 + l15] = 0;  // zero pad k=16..31
      }
    }
  }
}

// ---------------- main GEMM: out = xbf @ wbf^T + bias + LoRA(init via MFMA) ----------------
// 128x128 tile, BK=64, 4 waves (2x2), mfma_f32_16x16x32_bf16.
// LDS staged via global_load_lds with pre-swizzled SOURCE + XOR-swizzled ds_read
// (swizzle: chunk_in_row ^= (row&7) -> conflict-free stride-128B fragment reads).
__global__ __launch_bounds__(256) void k_gemm(const unsigned short* __restrict__ xbf,
                                              const unsigned short* __restrict__ wbf,
                                              const unsigned short* __restrict__ interbf,
                                              const unsigned short* __restrict__ abf,
                                              const float* __restrict__ bias,
                                              float* __restrict__ out) {
  __shared__ unsigned short As[128 * 64];
  __shared__ unsigned short Bs[128 * 64];
  const int tid  = threadIdx.x;
  const int lane = tid & 63;
  const int wv   = tid >> 6;
  const int wm   = wv >> 1, wn = wv & 1;
  const int l15  = lane & 15;
  const int hi   = lane >> 4;

  // XCD-aware bijective swizzle (grid = 2048, 2048 % 8 == 0)
  int bid  = blockIdx.x;
  int swzb = ((bid & 7) << 8) | (bid >> 3);  // cpx = 2048/8 = 256
  const int mt = swzb >> 4;                  // 128 M-tiles
  const int nt = swzb & 15;                  // 16 N-tiles
  const int mrow0 = mt << 7;
  const int ncol0 = nt << 7;
  const int bb = mrow0 >> 11;                // batch of this M-tile (128 | 2048)

  const int m0 = mrow0 + wm * 64;
  const int n0 = ncol0 + wn * 64;

  // ---- LoRA adaptation as accumulator init: acc = inter_frag x A_frag (K=16 zero-padded to 32)
  floatx4 acc[4][4];
  {
    bf16x8 la[4], lb[4];
    #pragma unroll
    for (int mi = 0; mi < 4; ++mi)
      la[mi] = *(const bf16x8*)(interbf + (size_t)(m0 + mi * 16 + l15) * 32 + hi * 8);
    #pragma unroll
    for (int ni = 0; ni < 4; ++ni)
      lb[ni] = *(const bf16x8*)(abf + ((size_t)bb * N_TOT + n0 + ni * 16 + l15) * 32 + hi * 8);
    floatx4 z = {0.f, 0.f, 0.f, 0.f};
    #pragma unroll
    for (int mi = 0; mi < 4; ++mi)
      #pragma unroll
      for (int ni = 0; ni < 4; ++ni)
        acc[mi][ni] = __builtin_amdgcn_mfma_f32_16x16x32_bf16(la[mi], lb[ni], z, 0, 0, 0);
  }

  // ---- staging pointers (pre-swizzled source so linear LDS == swizzled layout)
  const unsigned short* Ag = xbf + (size_t)mrow0 * K_TOT;
  const unsigned short* Bg = wbf + (size_t)ncol0 * K_TOT;
  const unsigned short* pA[4];
  const unsigned short* pB[4];
  int ldsOff[4];
  #pragma unroll
  for (int i = 0; i < 4; ++i) {
    int c   = i * 256 + wv * 64 + lane;      // chunk 0..1023 (16B each)
    int row = c >> 3;                        // tile row 0..127
    int k8  = (c & 7) ^ (row & 7);           // inverse-swizzled source chunk within row
    pA[i] = Ag + (size_t)row * K_TOT + k8 * 8;
    pB[i] = Bg + (size_t)row * K_TOT + k8 * 8;
    ldsOff[i] = (i * 256 + wv * 64) * 16;    // wave-uniform LDS byte base
  }

  for (int kt = 0; kt < K_TOT; kt += 64) {
    #pragma unroll
    for (int i = 0; i < 4; ++i) GLOAD_LDS16(pA[i] + kt, (char*)As + ldsOff[i]);
    #pragma unroll
    for (int i = 0; i < 4; ++i) GLOAD_LDS16(pB[i] + kt, (char*)Bs + ldsOff[i]);
    asm volatile("s_waitcnt vmcnt(0)" ::: "memory");
    __syncthreads();

    #pragma unroll
    for (int ks = 0; ks < 2; ++ks) {
      bf16x8 af[4], bfv[4];
      #pragma unroll
      for (int mi = 0; mi < 4; ++mi) {
        int row = wm * 64 + mi * 16 + l15;
        int k8  = (ks * 4 + hi) ^ (row & 7);
        af[mi] = *(const bf16x8*)((const char*)As + row * 128 + k8 * 16);
      }
      #pragma unroll
      for (int ni = 0; ni < 4; ++ni) {
        int row = wn * 64 + ni * 16 + l15;
        int k8  = (ks * 4 + hi) ^ (row & 7);
        bfv[ni] = *(const bf16x8*)((const char*)Bs + row * 128 + k8 * 16);
      }
      #pragma unroll
      for (int mi = 0; mi < 4; ++mi)
        #pragma unroll
        for (int ni = 0; ni < 4; ++ni)
          acc[mi][ni] = __builtin_amdgcn_mfma_f32_16x16x32_bf16(af[mi], bfv[ni], acc[mi][ni], 0, 0, 0);
    }
    __syncthreads();
  }

  // ---- epilogue: + bias, store f32
  #pragma unroll
  for (int ni = 0; ni < 4; ++ni) {
    int col = n0 + ni * 16 + l15;
    float bv = bias[col];
    #pragma unroll
    for (int mi = 0; mi < 4; ++mi) {
      int r0 = m0 + mi * 16 + hi * 4;
      #pragma unroll
      for (int j = 0; j < 4; ++j)
        out[(size_t)(r0 + j) * N_TOT + col] = acc[mi][ni][j] + bv;
    }
  }
}

// ---------------- launcher ----------------
extern "C" void kernel_launch(void* const* d_in, const int* in_sizes, int n_in,
                              void* d_out, int out_size, void* d_ws, size_t ws_size,
                              hipStream_t stream) {
  const float* x    = (const float*)d_in[0];   // [8,2048,2048]
  const float* Ap   = (const float*)d_in[1];   // [8,2048,16]
  const float* Bp   = (const float*)d_in[2];   // [8,16,2048]
  const float* W    = (const float*)d_in[3];   // [2048,2048]
  const float* bias = (const float*)d_in[4];   // [2048]
  float* out = (float*)d_out;

  // workspace layout (74.5 MiB total)
  char* ws = (char*)d_ws;
  unsigned short* xbf     = (unsigned short*)(ws);                         // 64 MiB
  unsigned short* wbf     = (unsigned short*)(ws + 67108864);              // 8 MiB
  unsigned short* abf     = (unsigned short*)(ws + 67108864 + 8388608);    // 1 MiB
  unsigned short* bpbf    = (unsigned short*)(ws + 67108864 + 8388608 + 1048576);            // 0.5 MiB
  unsigned short* interbf = (unsigned short*)(ws + 67108864 + 8388608 + 1048576 + 524288);   // 1 MiB

  // converts (all 8 elems/thread, exact grids)
  k_convert<<<dim3(16384), dim3(256), 0, stream>>>(x,  xbf,  4194304);  // 33.5M elems
  k_convert<<<dim3(2048),  dim3(256), 0, stream>>>(W,  wbf,   524288);  // 4.2M elems
  k_convert<<<dim3(128),   dim3(256), 0, stream>>>(Bp, bpbf,   32768);  // 262K elems
  k_convert_a<<<dim3(64),  dim3(256), 0, stream>>>(Ap, abf);            // 16384 rows

  // inter = x @ Bp^T (bf16 MFMA, f32 accum), padded to K=32
  k_inter<<<dim3(256), dim3(256), 0, stream>>>(xbf, bpbf, interbf);

  // main fused GEMM
  k_gemm<<<dim3(2048), dim3(256), 0, stream>>>(xbf, wbf, interbf, abf, bias, out);
}